// Round 8
// baseline (219.550 us; speedup 1.0000x reference)
//
#include <hip/hip_runtime.h>

#define N_NODES 100000
#define N_EDGES 1250000
#define D 64
#define NPB 256                  // nodes per coarse bucket (dst >> 8)
#define NB  391                  // ceil(N_NODES / NPB)
#define NPAD2 (NB * NPB)         // 100096
#define EPT 4                    // edges per thread in place
#define EPB (256 * EPT)          // 1024 edges per block
#define NBLK ((N_EDGES + EPB - 1) / EPB)   // 1221
#define CAP  4096                // static per-bucket capacity (mean 3197, +15 sigma)
#define CAPPAD 1792              // extra capacity for pad-to-8 (256*7)
#define CAPP (CAP + CAPPAD)      // 5888: per-bucket stride in ssp
#define DUMMY N_NODES            // featn[DUMMY] is a zero row

// ---------------- init: gcursor[b] = b*CAP ----------------
__global__ void init_kernel(int* __restrict__ gcursor) {
    int i = blockIdx.x * 256 + threadIdx.x;
    if (i < NB) gcursor[i] = i * CAP;
}

// ---------------- place: local counting sort, ascending-address emission ----------------
// static bucket windows [b*CAP, (b+1)*CAP); no pre-histogram needed
__global__ __launch_bounds__(256) void place_kernel(const int* __restrict__ src,
                                                    const int* __restrict__ dst,
                                                    int* __restrict__ gcursor,
                                                    unsigned int* __restrict__ packed) {
    __shared__ int h[512];                 // bin counts (padded to 512)
    __shared__ int ps[256];                // pair-scan workspace
    __shared__ int lstart[NB];             // local exclusive start per bin
    __shared__ int gbase[NB];              // reserved global base per bin
    __shared__ int lcur[NB];               // local scatter cursor
    __shared__ unsigned sortedv[EPB];      // locally-sorted packed values
    __shared__ unsigned short binof[EPB];  // bin of each sorted slot
    int t = threadIdx.x;
    h[t] = 0; h[t + 256] = 0;
    __syncthreads();

    int base = blockIdx.x * EPB;
    int d[EPT], s[EPT];
    #pragma unroll
    for (int i = 0; i < EPT; ++i) {
        int e = base + t + i * 256;
        if (e < N_EDGES) {
            d[i] = dst[e]; s[i] = src[e];
            atomicAdd(&h[d[i] >> 8], 1);
        } else d[i] = -1;
    }
    __syncthreads();

    // scan 512 bins with 256 threads: pair-combine then Hillis-Steele on pairs
    int a0 = h[2 * t], a1 = h[2 * t + 1];
    int pinc = a0 + a1;
    ps[t] = pinc;
    __syncthreads();
    for (int off = 1; off < 256; off <<= 1) {
        int y = (t >= off) ? ps[t - off] : 0;
        __syncthreads();
        pinc += y;
        ps[t] = pinc;
        __syncthreads();
    }
    int pexc = pinc - a0 - a1;
    if (2 * t < NB) {
        lstart[2 * t] = pexc;
        lcur[2 * t] = pexc;
        gbase[2 * t] = a0 ? atomicAdd(&gcursor[2 * t], a0) : 0;
    }
    if (2 * t + 1 < NB) {
        lstart[2 * t + 1] = pexc + a0;
        lcur[2 * t + 1] = pexc + a0;
        gbase[2 * t + 1] = a1 ? atomicAdd(&gcursor[2 * t + 1], a1) : 0;
    }
    __syncthreads();

    // local scatter into LDS (sorted by bin)
    #pragma unroll
    for (int i = 0; i < EPT; ++i) {
        if (d[i] >= 0) {
            int b = d[i] >> 8;
            int pos = atomicAdd(&lcur[b], 1);
            sortedv[pos] = ((unsigned)s[i] << 8) | (unsigned)(d[i] & 255);
            binof[pos] = (unsigned short)b;
        }
    }
    __syncthreads();

    // emission: consecutive k -> ascending global addresses (coalesced runs)
    int cnt = min(EPB, N_EDGES - base);
    for (int k = t; k < cnt; k += 256) {
        int b = binof[k];
        int gp = gbase[b] + (k - lstart[b]);
        if (gp < (b + 1) * CAP) packed[gp] = sortedv[k];   // capacity clamp (never hits)
    }
}

// ---------------- refine: per-bucket CSR padded to mult-of-8 + norm, 512 threads ----------------
__global__ __launch_bounds__(512) void refine_pad_kernel(const unsigned int* __restrict__ packed,
                                                         const int* __restrict__ gcursor,
                                                         int* __restrict__ ssp,
                                                         int* __restrict__ pbeg,
                                                         int* __restrict__ pdega,
                                                         float* __restrict__ norm) {
    __shared__ int h[NPB];
    __shared__ int sc[NPB];
    __shared__ int cur[NPB];
    int b = blockIdx.x, t = threadIdx.x;
    int beg = b * CAP, end = gcursor[b];
    if (t < NPB) h[t] = 0;
    __syncthreads();
    for (int j = beg + t; j < end; j += 512)
        atomicAdd(&h[packed[j] & 255], 1);
    __syncthreads();
    int deg = 0, pdeg = 0, inc = 0;
    if (t < NPB) {
        deg = h[t];
        pdeg = (deg + 7) & ~7;            // deg==0 -> 0 slots
        inc = pdeg;
        sc[t] = inc;
    }
    __syncthreads();
    for (int off = 1; off < 256; off <<= 1) {
        int y = (t < NPB && t >= off) ? sc[t - off] : 0;
        __syncthreads();
        if (t < NPB) { inc += y; sc[t] = inc; }
        __syncthreads();
    }
    int pb = 0;
    if (t < NPB) {
        int exc = inc - pdeg;
        pb = b * CAPP + exc;              // absolute padded begin (capacity layout)
        cur[t] = pb;
        int n = b * NPB + t;
        pbeg[n] = pb;
        pdega[n] = pdeg;
        if (n < N_NODES) norm[n] = rsqrtf((float)(deg < 1 ? 1 : deg));
    }
    __syncthreads();
    for (int j = beg + t; j < end; j += 512) {
        unsigned p = packed[j];
        int pos = atomicAdd(&cur[p & 255], 1);
        ssp[pos] = (int)(p >> 8);
    }
    __syncthreads();
    if (t < NPB) {
        int fend = pb + pdeg;             // fill pad slots with dummy (<=7 per node)
        for (int k = cur[t]; k < fend; ++k) ssp[k] = DUMMY;
    }
}

// ---------------- prep: featn[n][k] = bf16(feat[n][k]*norm[n]); rows >= N_NODES zeroed ----------------
__global__ __launch_bounds__(256) void prep_kernel(const float* __restrict__ feat,
                                                   const float* __restrict__ norm,
                                                   unsigned short* __restrict__ featn) {
    int g = blockIdx.x * 256 + threadIdx.x;       // < NPAD2*16
    int n = g >> 4;
    uint2 r = make_uint2(0u, 0u);
    if (n < N_NODES) {
        float nn = norm[n];
        float4 f = *(const float4*)&feat[(size_t)g * 4];
        auto cvt = [](float x) -> unsigned {
            unsigned u = __float_as_uint(x);
            return (u + 0x7fff + ((u >> 16) & 1)) >> 16;
        };
        r.x = cvt(f.x * nn) | (cvt(f.y * nn) << 16);
        r.y = cvt(f.z * nn) | (cvt(f.w * nn) << 16);
    }
    *(uint2*)&featn[(size_t)g * 4] = r;
}

#define ACC_EDGE(SSARR, J) do {                                       \
        int s_ = SSARR[(J)];                                          \
        uint2 r_ = *(const uint2*)&featn[(size_t)s_ * D + m * 4];     \
        acc.x += __uint_as_float(r_.x << 16);                         \
        acc.y += __uint_as_float(r_.x & 0xffff0000u);                 \
        acc.z += __uint_as_float(r_.y << 16);                         \
        acc.w += __uint_as_float(r_.y & 0xffff0000u);                 \
    } while (0)

// ---------------- gather (padded): no tail, 4-deep load pipeline ----------------
__global__ __launch_bounds__(256) void gather_pad_kernel(const unsigned short* __restrict__ featn,
                                                         const int* __restrict__ ssp,
                                                         const int* __restrict__ pbeg,
                                                         const int* __restrict__ pdega,
                                                         const float* __restrict__ norm,
                                                         float* __restrict__ out) {
    int n = blockIdx.x * 4 + (threadIdx.x >> 6);
    int lane = threadIdx.x & 63;
    if (n >= N_NODES) return;
    int beg = pbeg[n], end = beg + pdega[n];
    int q = lane >> 4, m = lane & 15;
    float4 acc = make_float4(0.f, 0.f, 0.f, 0.f);
    int j = beg;
    for (; j + 16 <= end; j += 16) {
        ACC_EDGE(ssp, j + q);
        ACC_EDGE(ssp, j + 4 + q);
        ACC_EDGE(ssp, j + 8 + q);
        ACC_EDGE(ssp, j + 12 + q);
    }
    if (j < end) {                 // exactly 8 remain
        ACC_EDGE(ssp, j + q);
        ACC_EDGE(ssp, j + 4 + q);
    }
    #pragma unroll
    for (int mask = 16; mask <= 32; mask <<= 1) {
        acc.x += __shfl_xor(acc.x, mask);
        acc.y += __shfl_xor(acc.y, mask);
        acc.z += __shfl_xor(acc.z, mask);
        acc.w += __shfl_xor(acc.w, mask);
    }
    if (q == 0) {
        float nn = norm[n];
        *(float4*)&out[(size_t)n * D + m * 4] =
            make_float4(acc.x * nn, acc.y * nn, acc.z * nn, acc.w * nn);
    }
}

// ---------------- GEMM: out = h @ W^T + bias, in-place on d_out ----------------
#define GPAD 68
__global__ __launch_bounds__(256) void gemm64_kernel(const float* __restrict__ weight,
                                                     const float* __restrict__ bias,
                                                     float* __restrict__ io) {
    __shared__ float Ht[D * GPAD];   // Ht[k][n]
    __shared__ float Wt[D * GPAD];   // Wt[k][d]
    int tid = threadIdx.x;
    int n0 = blockIdx.x * 64;
    int c = tid & 63;
    int r4 = tid >> 6;

    for (int dd = r4; dd < D; dd += 4)
        Wt[c * GPAD + dd] = weight[dd * D + c];
    for (int nl = r4; nl < 64; nl += 4) {
        int n = n0 + nl;
        Ht[c * GPAD + nl] = (n < N_NODES) ? io[(size_t)n * D + c] : 0.f;
    }
    __syncthreads();

    int tx = tid & 15, ty = tid >> 4;
    float acc[4][4] = {};
    #pragma unroll 8
    for (int k = 0; k < D; ++k) {
        float4 a = *(const float4*)&Ht[k * GPAD + ty * 4];
        float4 b = *(const float4*)&Wt[k * GPAD + tx * 4];
        acc[0][0] += a.x * b.x; acc[0][1] += a.x * b.y; acc[0][2] += a.x * b.z; acc[0][3] += a.x * b.w;
        acc[1][0] += a.y * b.x; acc[1][1] += a.y * b.y; acc[1][2] += a.y * b.z; acc[1][3] += a.y * b.w;
        acc[2][0] += a.z * b.x; acc[2][1] += a.z * b.y; acc[2][2] += a.z * b.z; acc[2][3] += a.z * b.w;
        acc[3][0] += a.w * b.x; acc[3][1] += a.w * b.y; acc[3][2] += a.w * b.z; acc[3][3] += a.w * b.w;
    }

    float4 bv = *(const float4*)&bias[tx * 4];
    #pragma unroll
    for (int i = 0; i < 4; ++i) {
        int n = n0 + ty * 4 + i;
        if (n < N_NODES) {
            *(float4*)&io[(size_t)n * D + tx * 4] =
                make_float4(acc[i][0] + bv.x, acc[i][1] + bv.y,
                            acc[i][2] + bv.z, acc[i][3] + bv.w);
        }
    }
}

extern "C" void kernel_launch(void* const* d_in, const int* in_sizes, int n_in,
                              void* d_out, int out_size, void* d_ws, size_t ws_size,
                              hipStream_t stream) {
    const float* feat   = (const float*)d_in[0];
    const int*   src    = (const int*)d_in[1];
    const int*   dst    = (const int*)d_in[2];
    const float* weight = (const float*)d_in[3];
    const float* bias   = (const float*)d_in[4];
    float* out = (float*)d_out;

    // workspace layout (4-byte units):
    //   gcursor[NB] | pbeg[NPAD2] | pdega[NPAD2] | norm[NPAD2] | ssp[NB*CAPP] | pad[1]
    //   | featn region (16B-aligned): packed[NB*CAP] overlays featn's first 6.4 MB
    //   (packed dead after refine; prep writes featn after)
    // high water ~= 10.41 MB + 12.81 MB = 23.2 MB
    int* w = (int*)d_ws;
    int*      gcursor = w;                                   // [NB]
    int*      pbeg    = gcursor + NB;                        // [NPAD2]
    int*      pdega   = pbeg + NPAD2;                        // [NPAD2]
    float*    norm    = (float*)(pdega + NPAD2);             // [NPAD2]
    int*      ssp     = (int*)(norm + NPAD2);                // [NB*CAPP]
    unsigned* packed  = (unsigned*)(ssp + (size_t)NB * CAPP + 1);  // +1 pad -> 16B aligned
    unsigned short* featn = (unsigned short*)packed;         // [NPAD2*D] bf16

    init_kernel      <<<2, 256, 0, stream>>>(gcursor);
    place_kernel     <<<NBLK, 256, 0, stream>>>(src, dst, gcursor, packed);
    refine_pad_kernel<<<NB, 512, 0, stream>>>(packed, gcursor, ssp, pbeg, pdega, norm);
    prep_kernel      <<<NPAD2 * 16 / 256, 256, 0, stream>>>(feat, norm, featn);
    gather_pad_kernel<<<(N_NODES + 3) / 4, 256, 0, stream>>>(featn, ssp, pbeg, pdega, norm, out);
    gemm64_kernel    <<<(N_NODES + 63) / 64, 256, 0, stream>>>(weight, bias, out);
}

// Round 9
// 184.662 us; speedup vs baseline: 1.1889x; 1.1889x over previous
//
#include <hip/hip_runtime.h>

#define N_NODES 100000
#define N_EDGES 1250000
#define D 64
#define NPB 256                  // nodes per coarse bucket (dst >> 8)
#define NB  391                  // ceil(N_NODES / NPB)
#define NPAD2 (NB * NPB)         // 100096
#define PTHREADS 512
#define EPT 8                    // edges per thread in place
#define EPB (PTHREADS * EPT)     // 4096 edges per block
#define NBLK ((N_EDGES + EPB - 1) / EPB)   // 306
#define CAP  4096                // static per-bucket capacity (mean 3197, +15 sigma)
#define CAPPAD 1792              // extra capacity for pad-to-8 (256*7)
#define CAPP (CAP + CAPPAD)      // 5888: per-bucket stride in ssp
#define DUMMY N_NODES            // featn[DUMMY] is a zero row

// ---------------- init: gcursor[b] = b*CAP ----------------
__global__ void init_kernel(int* __restrict__ gcursor) {
    int i = blockIdx.x * 256 + threadIdx.x;
    if (i < NB) gcursor[i] = i * CAP;
}

// ---------------- place: local counting sort, ascending-address emission ----------------
// static bucket windows [b*CAP, (b+1)*CAP); 306 blocks x 512 threads
__global__ __launch_bounds__(PTHREADS) void place_kernel(const int* __restrict__ src,
                                                         const int* __restrict__ dst,
                                                         int* __restrict__ gcursor,
                                                         unsigned int* __restrict__ packed) {
    __shared__ int h[512];                 // bin counts (padded to 512)
    __shared__ int ps[256];                // pair-scan workspace
    __shared__ int lstart[NB];             // local exclusive start per bin
    __shared__ int gbase[NB];              // reserved global base per bin
    __shared__ int lcur[NB];               // local scatter cursor
    __shared__ unsigned sortedv[EPB];      // 16 KB locally-sorted packed values
    __shared__ unsigned short binof[EPB];  // 8 KB bin of each sorted slot
    int t = threadIdx.x;
    h[t] = 0;
    __syncthreads();

    int base = blockIdx.x * EPB;
    int d[EPT], s[EPT];
    #pragma unroll
    for (int i = 0; i < EPT; ++i) {
        int e = base + t + i * PTHREADS;
        if (e < N_EDGES) {
            d[i] = dst[e]; s[i] = src[e];
            atomicAdd(&h[d[i] >> 8], 1);
        } else d[i] = -1;
    }
    __syncthreads();

    // scan 512 bins with first 256 threads: pair-combine + Hillis-Steele on pairs
    int a0 = 0, a1 = 0, pinc = 0;
    if (t < 256) {
        a0 = h[2 * t]; a1 = h[2 * t + 1];
        pinc = a0 + a1;
        ps[t] = pinc;
    }
    __syncthreads();
    for (int off = 1; off < 256; off <<= 1) {
        int y = (t < 256 && t >= off) ? ps[t - off] : 0;
        __syncthreads();
        if (t < 256) { pinc += y; ps[t] = pinc; }
        __syncthreads();
    }
    if (t < 256) {
        int pexc = pinc - a0 - a1;
        if (2 * t < NB) {
            lstart[2 * t] = pexc;
            lcur[2 * t] = pexc;
            gbase[2 * t] = a0 ? atomicAdd(&gcursor[2 * t], a0) : 0;
        }
        if (2 * t + 1 < NB) {
            lstart[2 * t + 1] = pexc + a0;
            lcur[2 * t + 1] = pexc + a0;
            gbase[2 * t + 1] = a1 ? atomicAdd(&gcursor[2 * t + 1], a1) : 0;
        }
    }
    __syncthreads();

    // local scatter into LDS (sorted by bin)
    #pragma unroll
    for (int i = 0; i < EPT; ++i) {
        if (d[i] >= 0) {
            int b = d[i] >> 8;
            int pos = atomicAdd(&lcur[b], 1);
            sortedv[pos] = ((unsigned)s[i] << 8) | (unsigned)(d[i] & 255);
            binof[pos] = (unsigned short)b;
        }
    }
    __syncthreads();

    // emission: consecutive k -> ascending global addresses (coalesced runs)
    int cnt = min(EPB, N_EDGES - base);
    for (int k = t; k < cnt; k += PTHREADS) {
        int b = binof[k];
        int gp = gbase[b] + (k - lstart[b]);
        if (gp < (b + 1) * CAP) packed[gp] = sortedv[k];   // capacity clamp (never hits)
    }
}

// ---------------- refine: per-bucket CSR padded to mult-of-8 + norm, 1024 threads ----------------
__global__ __launch_bounds__(1024) void refine_pad_kernel(const unsigned int* __restrict__ packed,
                                                          const int* __restrict__ gcursor,
                                                          int* __restrict__ ssp,
                                                          int* __restrict__ pbeg,
                                                          int* __restrict__ pdega,
                                                          float* __restrict__ norm) {
    __shared__ int h[NPB];
    __shared__ int sc[NPB];
    __shared__ int cur[NPB];
    int b = blockIdx.x, t = threadIdx.x;
    int beg = b * CAP;
    int end = min(gcursor[b], (b + 1) * CAP);
    if (t < NPB) h[t] = 0;
    __syncthreads();
    for (int j = beg + t; j < end; j += 1024)
        atomicAdd(&h[packed[j] & 255], 1);
    __syncthreads();
    int deg = 0, pdeg = 0, inc = 0;
    if (t < NPB) {
        deg = h[t];
        pdeg = (deg + 7) & ~7;            // deg==0 -> 0 slots
        inc = pdeg;
        sc[t] = inc;
    }
    __syncthreads();
    for (int off = 1; off < 256; off <<= 1) {
        int y = (t < NPB && t >= off) ? sc[t - off] : 0;
        __syncthreads();
        if (t < NPB) { inc += y; sc[t] = inc; }
        __syncthreads();
    }
    int pb = 0;
    if (t < NPB) {
        int exc = inc - pdeg;
        pb = b * CAPP + exc;              // absolute padded begin (capacity layout)
        cur[t] = pb;
        int n = b * NPB + t;
        pbeg[n] = pb;
        pdega[n] = pdeg;
        if (n < N_NODES) norm[n] = rsqrtf((float)(deg < 1 ? 1 : deg));
    }
    __syncthreads();
    for (int j = beg + t; j < end; j += 1024) {
        unsigned p = packed[j];
        int pos = atomicAdd(&cur[p & 255], 1);
        ssp[pos] = (int)(p >> 8);
    }
    __syncthreads();
    if (t < NPB) {
        int fend = pb + pdeg;             // fill pad slots with dummy (<=7 per node)
        for (int k = cur[t]; k < fend; ++k) ssp[k] = DUMMY;
    }
}

// ---------------- prep: featn[n][k] = bf16(feat[n][k]*norm[n]); rows >= N_NODES zeroed ----------------
__global__ __launch_bounds__(256) void prep_kernel(const float* __restrict__ feat,
                                                   const float* __restrict__ norm,
                                                   unsigned short* __restrict__ featn) {
    int g = blockIdx.x * 256 + threadIdx.x;       // < NPAD2*16
    int n = g >> 4;
    uint2 r = make_uint2(0u, 0u);
    if (n < N_NODES) {
        float nn = norm[n];
        float4 f = *(const float4*)&feat[(size_t)g * 4];
        auto cvt = [](float x) -> unsigned {
            unsigned u = __float_as_uint(x);
            return (u + 0x7fff + ((u >> 16) & 1)) >> 16;
        };
        r.x = cvt(f.x * nn) | (cvt(f.y * nn) << 16);
        r.y = cvt(f.z * nn) | (cvt(f.w * nn) << 16);
    }
    *(uint2*)&featn[(size_t)g * 4] = r;
}

#define ACC_EDGE(SSARR, J) do {                                       \
        int s_ = SSARR[(J)];                                          \
        uint2 r_ = *(const uint2*)&featn[(size_t)s_ * D + m * 4];     \
        acc.x += __uint_as_float(r_.x << 16);                         \
        acc.y += __uint_as_float(r_.x & 0xffff0000u);                 \
        acc.z += __uint_as_float(r_.y << 16);                         \
        acc.w += __uint_as_float(r_.y & 0xffff0000u);                 \
    } while (0)

// ---------------- gather (padded): no tail, 4-deep load pipeline ----------------
__global__ __launch_bounds__(256) void gather_pad_kernel(const unsigned short* __restrict__ featn,
                                                         const int* __restrict__ ssp,
                                                         const int* __restrict__ pbeg,
                                                         const int* __restrict__ pdega,
                                                         const float* __restrict__ norm,
                                                         float* __restrict__ out) {
    int n = blockIdx.x * 4 + (threadIdx.x >> 6);
    int lane = threadIdx.x & 63;
    if (n >= N_NODES) return;
    int beg = pbeg[n], end = beg + pdega[n];
    int q = lane >> 4, m = lane & 15;
    float4 acc = make_float4(0.f, 0.f, 0.f, 0.f);
    int j = beg;
    for (; j + 16 <= end; j += 16) {
        ACC_EDGE(ssp, j + q);
        ACC_EDGE(ssp, j + 4 + q);
        ACC_EDGE(ssp, j + 8 + q);
        ACC_EDGE(ssp, j + 12 + q);
    }
    if (j < end) {                 // exactly 8 remain
        ACC_EDGE(ssp, j + q);
        ACC_EDGE(ssp, j + 4 + q);
    }
    #pragma unroll
    for (int mask = 16; mask <= 32; mask <<= 1) {
        acc.x += __shfl_xor(acc.x, mask);
        acc.y += __shfl_xor(acc.y, mask);
        acc.z += __shfl_xor(acc.z, mask);
        acc.w += __shfl_xor(acc.w, mask);
    }
    if (q == 0) {
        float nn = norm[n];
        *(float4*)&out[(size_t)n * D + m * 4] =
            make_float4(acc.x * nn, acc.y * nn, acc.z * nn, acc.w * nn);
    }
}

// ---------------- GEMM: out = h @ W^T + bias, in-place on d_out ----------------
#define GPAD 68
__global__ __launch_bounds__(256) void gemm64_kernel(const float* __restrict__ weight,
                                                     const float* __restrict__ bias,
                                                     float* __restrict__ io) {
    __shared__ float Ht[D * GPAD];   // Ht[k][n]
    __shared__ float Wt[D * GPAD];   // Wt[k][d]
    int tid = threadIdx.x;
    int n0 = blockIdx.x * 64;
    int c = tid & 63;
    int r4 = tid >> 6;

    for (int dd = r4; dd < D; dd += 4)
        Wt[c * GPAD + dd] = weight[dd * D + c];
    for (int nl = r4; nl < 64; nl += 4) {
        int n = n0 + nl;
        Ht[c * GPAD + nl] = (n < N_NODES) ? io[(size_t)n * D + c] : 0.f;
    }
    __syncthreads();

    int tx = tid & 15, ty = tid >> 4;
    float acc[4][4] = {};
    #pragma unroll 8
    for (int k = 0; k < D; ++k) {
        float4 a = *(const float4*)&Ht[k * GPAD + ty * 4];
        float4 b = *(const float4*)&Wt[k * GPAD + tx * 4];
        acc[0][0] += a.x * b.x; acc[0][1] += a.x * b.y; acc[0][2] += a.x * b.z; acc[0][3] += a.x * b.w;
        acc[1][0] += a.y * b.x; acc[1][1] += a.y * b.y; acc[1][2] += a.y * b.z; acc[1][3] += a.y * b.w;
        acc[2][0] += a.z * b.x; acc[2][1] += a.z * b.y; acc[2][2] += a.z * b.z; acc[2][3] += a.z * b.w;
        acc[3][0] += a.w * b.x; acc[3][1] += a.w * b.y; acc[3][2] += a.w * b.z; acc[3][3] += a.w * b.w;
    }

    float4 bv = *(const float4*)&bias[tx * 4];
    #pragma unroll
    for (int i = 0; i < 4; ++i) {
        int n = n0 + ty * 4 + i;
        if (n < N_NODES) {
            *(float4*)&io[(size_t)n * D + tx * 4] =
                make_float4(acc[i][0] + bv.x, acc[i][1] + bv.y,
                            acc[i][2] + bv.z, acc[i][3] + bv.w);
        }
    }
}

extern "C" void kernel_launch(void* const* d_in, const int* in_sizes, int n_in,
                              void* d_out, int out_size, void* d_ws, size_t ws_size,
                              hipStream_t stream) {
    const float* feat   = (const float*)d_in[0];
    const int*   src    = (const int*)d_in[1];
    const int*   dst    = (const int*)d_in[2];
    const float* weight = (const float*)d_in[3];
    const float* bias   = (const float*)d_in[4];
    float* out = (float*)d_out;

    // workspace layout (4-byte units):
    //   gcursor[NB] | pbeg[NPAD2] | pdega[NPAD2] | norm[NPAD2] | ssp[NB*CAPP] | pad[1]
    //   | featn region (16B-aligned): packed[NB*CAP] overlays featn's first 6.4 MB
    //   (packed dead after refine; prep writes featn after)
    // high water ~= 10.41 MB + 12.81 MB = 23.2 MB
    int* w = (int*)d_ws;
    int*      gcursor = w;                                   // [NB]
    int*      pbeg    = gcursor + NB;                        // [NPAD2]
    int*      pdega   = pbeg + NPAD2;                        // [NPAD2]
    float*    norm    = (float*)(pdega + NPAD2);             // [NPAD2]
    int*      ssp     = (int*)(norm + NPAD2);                // [NB*CAPP]
    unsigned* packed  = (unsigned*)(ssp + (size_t)NB * CAPP + 1);  // +1 pad -> 16B aligned
    unsigned short* featn = (unsigned short*)packed;         // [NPAD2*D] bf16

    init_kernel      <<<2, 256, 0, stream>>>(gcursor);
    place_kernel     <<<NBLK, PTHREADS, 0, stream>>>(src, dst, gcursor, packed);
    refine_pad_kernel<<<NB, 1024, 0, stream>>>(packed, gcursor, ssp, pbeg, pdega, norm);
    prep_kernel      <<<NPAD2 * 16 / 256, 256, 0, stream>>>(feat, norm, featn);
    gather_pad_kernel<<<(N_NODES + 3) / 4, 256, 0, stream>>>(featn, ssp, pbeg, pdega, norm, out);
    gemm64_kernel    <<<(N_NODES + 63) / 64, 256, 0, stream>>>(weight, bias, out);
}

// Round 10
// 169.670 us; speedup vs baseline: 1.2940x; 1.0884x over previous
//
#include <hip/hip_runtime.h>

#define N_NODES 100000
#define N_EDGES 1250000
#define D 64
#define NPB 256                  // nodes per coarse bucket (dst >> 8)
#define NB  391                  // ceil(N_NODES / NPB)
#define NPAD2 (NB * NPB)         // 100096
#define PTHREADS 512
#define EPT 8                    // edges per thread in place
#define EPB (PTHREADS * EPT)     // 4096 edges per block
#define NBLK ((N_EDGES + EPB - 1) / EPB)   // 306
#define CAP  4096                // static per-bucket capacity (mean 3197, +15 sigma)
#define CAPPAD 1792              // extra capacity for pad-to-8 (256*7)
#define CAPP (CAP + CAPPAD)      // 5888: per-bucket stride in ssp
#define DUMMY N_NODES            // featn[DUMMY] is a zero row
#define HP 68                    // LDS leading-dim pad (16B-aligned float4 rows)

// ---------------- init: gcursor[b] = b*CAP ----------------
__global__ void init_kernel(int* __restrict__ gcursor) {
    int i = blockIdx.x * 256 + threadIdx.x;
    if (i < NB) gcursor[i] = i * CAP;
}

// ---------------- place: local counting sort, ascending-address emission ----------------
__global__ __launch_bounds__(PTHREADS) void place_kernel(const int* __restrict__ src,
                                                         const int* __restrict__ dst,
                                                         int* __restrict__ gcursor,
                                                         unsigned int* __restrict__ packed) {
    __shared__ int h[512];
    __shared__ int ps[256];
    __shared__ int lstart[NB];
    __shared__ int gbase[NB];
    __shared__ int lcur[NB];
    __shared__ unsigned sortedv[EPB];
    __shared__ unsigned short binof[EPB];
    int t = threadIdx.x;
    h[t] = 0;
    __syncthreads();

    int base = blockIdx.x * EPB;
    int d[EPT], s[EPT];
    #pragma unroll
    for (int i = 0; i < EPT; ++i) {
        int e = base + t + i * PTHREADS;
        if (e < N_EDGES) {
            d[i] = dst[e]; s[i] = src[e];
            atomicAdd(&h[d[i] >> 8], 1);
        } else d[i] = -1;
    }
    __syncthreads();

    int a0 = 0, a1 = 0, pinc = 0;
    if (t < 256) {
        a0 = h[2 * t]; a1 = h[2 * t + 1];
        pinc = a0 + a1;
        ps[t] = pinc;
    }
    __syncthreads();
    for (int off = 1; off < 256; off <<= 1) {
        int y = (t < 256 && t >= off) ? ps[t - off] : 0;
        __syncthreads();
        if (t < 256) { pinc += y; ps[t] = pinc; }
        __syncthreads();
    }
    if (t < 256) {
        int pexc = pinc - a0 - a1;
        if (2 * t < NB) {
            lstart[2 * t] = pexc;
            lcur[2 * t] = pexc;
            gbase[2 * t] = a0 ? atomicAdd(&gcursor[2 * t], a0) : 0;
        }
        if (2 * t + 1 < NB) {
            lstart[2 * t + 1] = pexc + a0;
            lcur[2 * t + 1] = pexc + a0;
            gbase[2 * t + 1] = a1 ? atomicAdd(&gcursor[2 * t + 1], a1) : 0;
        }
    }
    __syncthreads();

    #pragma unroll
    for (int i = 0; i < EPT; ++i) {
        if (d[i] >= 0) {
            int b = d[i] >> 8;
            int pos = atomicAdd(&lcur[b], 1);
            sortedv[pos] = ((unsigned)s[i] << 8) | (unsigned)(d[i] & 255);
            binof[pos] = (unsigned short)b;
        }
    }
    __syncthreads();

    int cnt = min(EPB, N_EDGES - base);
    for (int k = t; k < cnt; k += PTHREADS) {
        int b = binof[k];
        int gp = gbase[b] + (k - lstart[b]);
        if (gp < (b + 1) * CAP) packed[gp] = sortedv[k];
    }
}

// ---------------- refine + fused prep: padded CSR + norm + bf16 feat rows ----------------
__global__ __launch_bounds__(1024) void refine_pad_kernel(const unsigned int* __restrict__ packed,
                                                          const int* __restrict__ gcursor,
                                                          int* __restrict__ ssp,
                                                          int* __restrict__ pbeg,
                                                          int* __restrict__ pdega,
                                                          float* __restrict__ norm,
                                                          const float* __restrict__ feat,
                                                          unsigned short* __restrict__ featn) {
    __shared__ int h[NPB];
    __shared__ int sc[NPB];
    __shared__ int cur[NPB];
    __shared__ float normf[NPB];
    int b = blockIdx.x, t = threadIdx.x;
    int beg = b * CAP;
    int end = min(gcursor[b], (b + 1) * CAP);
    if (t < NPB) h[t] = 0;
    __syncthreads();
    for (int j = beg + t; j < end; j += 1024)
        atomicAdd(&h[packed[j] & 255], 1);
    __syncthreads();
    int deg = 0, pdeg = 0, inc = 0;
    if (t < NPB) {
        deg = h[t];
        pdeg = (deg + 7) & ~7;
        inc = pdeg;
        sc[t] = inc;
    }
    __syncthreads();
    for (int off = 1; off < 256; off <<= 1) {
        int y = (t < NPB && t >= off) ? sc[t - off] : 0;
        __syncthreads();
        if (t < NPB) { inc += y; sc[t] = inc; }
        __syncthreads();
    }
    int pb = 0;
    if (t < NPB) {
        int exc = inc - pdeg;
        pb = b * CAPP + exc;
        cur[t] = pb;
        int n = b * NPB + t;
        pbeg[n] = pb;
        pdega[n] = pdeg;
        float nv = rsqrtf((float)(deg < 1 ? 1 : deg));
        norm[n] = nv;
        normf[t] = nv;
    }
    __syncthreads();
    for (int j = beg + t; j < end; j += 1024) {
        unsigned p = packed[j];
        int pos = atomicAdd(&cur[p & 255], 1);
        ssp[pos] = (int)(p >> 8);
    }
    __syncthreads();
    if (t < NPB) {
        int fend = pb + pdeg;
        for (int k = cur[t]; k < fend; ++k) ssp[k] = DUMMY;
    }

    // fused prep for this bucket's 256 nodes (rows >= N_NODES zeroed)
    int n0 = b * NPB;
    for (int idx = t; idx < NPB * 16; idx += 1024) {
        int nl = idx >> 4;
        int n = n0 + nl;
        uint2 r = make_uint2(0u, 0u);
        if (n < N_NODES) {
            float nn = normf[nl];
            float4 f = ((const float4*)feat)[(size_t)n * 16 + (idx & 15)];
            auto cvt = [](float x) -> unsigned {
                unsigned u = __float_as_uint(x);
                return (u + 0x7fff + ((u >> 16) & 1)) >> 16;
            };
            r.x = cvt(f.x * nn) | (cvt(f.y * nn) << 16);
            r.y = cvt(f.z * nn) | (cvt(f.w * nn) << 16);
        }
        ((uint2*)featn)[(size_t)n * 16 + (idx & 15)] = r;
    }
}

// ---------------- fused gather + GEMM: 64 nodes per 1024-thread block ----------------
#define ACC_EDGE(ACC, J) do {                                         \
        int s_ = ssp[(J)];                                            \
        uint2 r_ = *(const uint2*)&featn[(size_t)s_ * D + m * 4];     \
        ACC.x += __uint_as_float(r_.x << 16);                         \
        ACC.y += __uint_as_float(r_.x & 0xffff0000u);                 \
        ACC.z += __uint_as_float(r_.y << 16);                         \
        ACC.w += __uint_as_float(r_.y & 0xffff0000u);                 \
    } while (0)
#define ACC4(ACC, J) { ACC_EDGE(ACC, (J) + q); ACC_EDGE(ACC, (J) + 4 + q); \
                       ACC_EDGE(ACC, (J) + 8 + q); ACC_EDGE(ACC, (J) + 12 + q); }
#define ACC2(ACC, J) { ACC_EDGE(ACC, (J) + q); ACC_EDGE(ACC, (J) + 4 + q); }

__global__ __launch_bounds__(1024) void gather_gemm_kernel(const unsigned short* __restrict__ featn,
                                                           const int* __restrict__ ssp,
                                                           const int* __restrict__ pbeg,
                                                           const int* __restrict__ pdega,
                                                           const float* __restrict__ norm,
                                                           const float* __restrict__ weight,
                                                           const float* __restrict__ bias,
                                                           float* __restrict__ out) {
    __shared__ float Hcol[D * HP];   // Hcol[k][n_local]
    __shared__ float Wt[D * HP];     // Wt[k][d]
    int tid = threadIdx.x;
    int base = blockIdx.x * 64;

    // stage W^T (k-major) with all 1024 threads
    #pragma unroll
    for (int i = tid; i < D * D; i += 1024) {
        int c = i & 63, dd = i >> 6;
        Wt[c * HP + dd] = weight[dd * D + c];
    }

    // phase 1: gather. wave w handles 4 nodes, processed as 2 interleaved pairs.
    int w = tid >> 6;
    int lane = tid & 63;
    int q = lane >> 4, m = lane & 15;

    #pragma unroll
    for (int pr = 0; pr < 2; ++pr) {
        int nA = base + w * 4 + pr * 2;
        int nB = nA + 1;
        int begA = pbeg[nA], endA = begA + pdega[nA];
        int begB = pbeg[nB], endB = begB + pdega[nB];
        float4 aA = make_float4(0.f, 0.f, 0.f, 0.f);
        float4 aB = make_float4(0.f, 0.f, 0.f, 0.f);
        int jA = begA, jB = begB;
        while (jA + 16 <= endA && jB + 16 <= endB) {   // 8 row-loads in flight
            ACC4(aA, jA); ACC4(aB, jB);
            jA += 16; jB += 16;
        }
        for (; jA + 16 <= endA; jA += 16) ACC4(aA, jA);
        for (; jB + 16 <= endB; jB += 16) ACC4(aB, jB);
        if (jA < endA) ACC2(aA, jA);                    // exactly 8 remain
        if (jB < endB) ACC2(aB, jB);

        #pragma unroll
        for (int mask = 16; mask <= 32; mask <<= 1) {
            aA.x += __shfl_xor(aA.x, mask); aA.y += __shfl_xor(aA.y, mask);
            aA.z += __shfl_xor(aA.z, mask); aA.w += __shfl_xor(aA.w, mask);
            aB.x += __shfl_xor(aB.x, mask); aB.y += __shfl_xor(aB.y, mask);
            aB.z += __shfl_xor(aB.z, mask); aB.w += __shfl_xor(aB.w, mask);
        }
        float nnA = norm[nA], nnB = norm[nB];
        // lane (q,m) writes component q of column group m -> Hcol[4m+q][nl]
        float hA = (q == 0) ? aA.x : (q == 1) ? aA.y : (q == 2) ? aA.z : aA.w;
        float hB = (q == 0) ? aB.x : (q == 1) ? aB.y : (q == 2) ? aB.z : aB.w;
        int k = 4 * m + q;
        Hcol[k * HP + (w * 4 + pr * 2)]     = hA * nnA;
        Hcol[k * HP + (w * 4 + pr * 2 + 1)] = hB * nnB;
    }
    __syncthreads();

    // phase 2: 64x64 GEMM from LDS, first 256 threads, 4x4 register tiles
    if (tid < 256) {
        int tx = tid & 15, ty = tid >> 4;
        float acc[4][4] = {};
        #pragma unroll 8
        for (int k = 0; k < D; ++k) {
            float4 a = *(const float4*)&Hcol[k * HP + ty * 4];
            float4 b = *(const float4*)&Wt[k * HP + tx * 4];
            acc[0][0] += a.x * b.x; acc[0][1] += a.x * b.y; acc[0][2] += a.x * b.z; acc[0][3] += a.x * b.w;
            acc[1][0] += a.y * b.x; acc[1][1] += a.y * b.y; acc[1][2] += a.y * b.z; acc[1][3] += a.y * b.w;
            acc[2][0] += a.z * b.x; acc[2][1] += a.z * b.y; acc[2][2] += a.z * b.z; acc[2][3] += a.z * b.w;
            acc[3][0] += a.w * b.x; acc[3][1] += a.w * b.y; acc[3][2] += a.w * b.z; acc[3][3] += a.w * b.w;
        }
        float4 bv = *(const float4*)&bias[tx * 4];
        #pragma unroll
        for (int i = 0; i < 4; ++i) {
            int n = base + ty * 4 + i;
            if (n < N_NODES) {
                *(float4*)&out[(size_t)n * D + tx * 4] =
                    make_float4(acc[i][0] + bv.x, acc[i][1] + bv.y,
                                acc[i][2] + bv.z, acc[i][3] + bv.w);
            }
        }
    }
}

extern "C" void kernel_launch(void* const* d_in, const int* in_sizes, int n_in,
                              void* d_out, int out_size, void* d_ws, size_t ws_size,
                              hipStream_t stream) {
    const float* feat   = (const float*)d_in[0];
    const int*   src    = (const int*)d_in[1];
    const int*   dst    = (const int*)d_in[2];
    const float* weight = (const float*)d_in[3];
    const float* bias   = (const float*)d_in[4];
    float* out = (float*)d_out;

    // workspace layout (4-byte units), no overlays; high water ~29.6 MB
    int* w = (int*)d_ws;
    int*      gcursor = w;                                   // [NB]
    int*      pbeg    = gcursor + NB;                        // [NPAD2]
    int*      pdega   = pbeg + NPAD2;                        // [NPAD2]
    float*    norm    = (float*)(pdega + NPAD2);             // [NPAD2]
    int*      ssp     = (int*)(norm + NPAD2);                // [NB*CAPP]
    unsigned* packed  = (unsigned*)(ssp + (size_t)NB * CAPP);// [NB*CAP]
    size_t featn_off = (size_t)NB + 3 * (size_t)NPAD2 + (size_t)NB * CAPP + (size_t)NB * CAP;
    featn_off = (featn_off + 3) & ~(size_t)3;                // 16B-align
    unsigned short* featn = (unsigned short*)(w + featn_off);// [NPAD2*D] bf16

    init_kernel       <<<2, 256, 0, stream>>>(gcursor);
    place_kernel      <<<NBLK, PTHREADS, 0, stream>>>(src, dst, gcursor, packed);
    refine_pad_kernel <<<NB, 1024, 0, stream>>>(packed, gcursor, ssp, pbeg, pdega, norm, feat, featn);
    gather_gemm_kernel<<<(N_NODES + 63) / 64, 1024, 0, stream>>>(featn, ssp, pbeg, pdega, norm,
                                                                 weight, bias, out);
}